// Round 1
// baseline (168.675 us; speedup 1.0000x reference)
//
#include <hip/hip_runtime.h>

#define T_LEN   65536
#define BATCH   256
#define P       64
#define K1_LEN  8192
#define K1_THREADS 256
#define W_TILE  1024
#define BCHUNK  8
#define VOFF    65536          // V2 stored at R[VOFF..VOFF+64]
#define V3OFF   (VOFF + 80)    // V3 stored at R[V3OFF..V3OFF+64]

typedef float f4 __attribute__((ext_vector_type(4)));

// ---------------------------------------------------------------------------
// means[t] = bias * R[t] where R is the STEP RESPONSE of the AR(64) filter:
//   R[t] = sum_k params[k]*R[t-1-k] + 1,  R[t<0] = 0
// Extension identity:
//   R[L+tau] = R[tau] + sum_{i=0}^{64} V[i]*R[tau-i]
//   V[j] = W0[j] - W0[j-1],  W0[j] = sum_{m=0}^{63-j} params[m+j]*R[L-1-m]
// R6: the two grid-wide ar_double levels (16384, 32768) are ELIMINATED.
// ar_k1 now also derives V2 (level 16384), the level-2 tail R[32640..32768),
// and V3 (level 32768) from the captured tail R[16192..16384) — same fma
// order as ar_double, so bitwise-identical results. The output kernel
// reconstructs bias*R for its 1024-wide t-tile in LDS (<=130 fma/elem,
// hidden under the 128 MiB stream) and reuses it across 8 batch rows.
// ---------------------------------------------------------------------------

__global__ __launch_bounds__(K1_THREADS, 1) void ar_k1(const float* __restrict__ params,
                                                       float* __restrict__ R) {
    __shared__ __align__(16) float Rl[K1_LEN];
    __shared__ float p[128];          // zero-padded: p[64..127] = 0 masks m+j>63
    __shared__ float Wp[64][4];
    __shared__ __align__(16) float Vs[68];
    __shared__ __align__(16) float tailb[192];   // R[16192..16384)
    __shared__ float t3[128];                    // R[32640..32768)
    const int tid = threadIdx.x;
    if (tid < 128) p[tid] = (tid < P) ? params[tid] : 0.f;
    __syncthreads();

    // Serial stage: lane k holds transposed-form state z_{k+1}.
    if (tid < 64) {
        float z = 0.f;
        const float pk = p[tid];
        for (int t = 0; t < 64; ++t) {
            float y  = __shfl(z, 0) + 1.0f;   // R[t]
            float zn = __shfl_down(z, 1);
            if (tid == 63) zn = 0.f;
            z = fmaf(pk, y, zn);
            if (tid == 0) Rl[t] = y;
        }
    }
    __syncthreads();

    for (int L = 64; L <= K1_LEN; L <<= 1) {
        const bool last = (L == K1_LEN);   // last level streams to global
        // ---- V taps, wave-parallel ----
        {
            const int j = tid >> 2, c = tid & 3;
            const int mbase = c << 4;
            float w = 0.f;
            #pragma unroll
            for (int mm = 0; mm < 16; ++mm) {
                const int m = mbase + mm;
                w = fmaf(p[m + j], Rl[L - 1 - m], w);  // p pad masks m+j>63
            }
            Wp[j][c] = w;
        }
        __syncthreads();
        if (tid <= P) {
            const float wj  = (tid < P)
                ? (Wp[tid][0] + Wp[tid][1] + Wp[tid][2] + Wp[tid][3]) : 0.f;
            const float wm1 = (tid >= 1)
                ? (Wp[tid-1][0] + Wp[tid-1][1] + Wp[tid-1][2] + Wp[tid-1][3]) : 0.f;
            Vs[tid] = wj - wm1;
        }
        __syncthreads();
        // ---- boundary outputs tau in [0,64) ----
        if (tid < P) {
            const int tau = tid;
            float acc = Rl[tau];
            #pragma unroll
            for (int i = 0; i < P; ++i) {
                const int idx = (tau - i) > 0 ? (tau - i) : 0;
                const float v = (i <= tau) ? Vs[i] : 0.f;
                acc = fmaf(v, Rl[idx], acc);
            }
            if (last) R[L + tau] = acc; else Rl[L + tau] = acc;
        }
        // ---- blocked outputs tau in [64,L) ----
        {
            const f4* __restrict__ Rl4 = reinterpret_cast<const f4*>(Rl);
            f4* __restrict__ Rl4w = reinterpret_cast<f4*>(Rl);
            f4* __restrict__ Rg4  = reinterpret_cast<f4*>(R);
            const f4* __restrict__ V4 = reinterpret_cast<const f4*>(Vs);
            const int nq = (L - 64) >> 2;
            #pragma unroll 1
            for (int q = tid; q < nq; q += K1_THREADS) {
                f4 w4[17];
                #pragma unroll
                for (int j = 0; j < 17; ++j) w4[j] = Rl4[q + j];
                float a0 = w4[16].x, a1 = w4[16].y, a2 = w4[16].z, a3 = w4[16].w;
                #pragma unroll
                for (int g = 0; g < 16; ++g) {   // i = 4g..4g+3
                    const f4 v  = V4[g];
                    const f4 hi = w4[16 - g];
                    const f4 lo = w4[15 - g];
                    a0 = fmaf(v.x, hi.x, a0); a1 = fmaf(v.x, hi.y, a1);
                    a2 = fmaf(v.x, hi.z, a2); a3 = fmaf(v.x, hi.w, a3);
                    a0 = fmaf(v.y, lo.w, a0); a1 = fmaf(v.y, hi.x, a1);
                    a2 = fmaf(v.y, hi.y, a2); a3 = fmaf(v.y, hi.z, a3);
                    a0 = fmaf(v.z, lo.z, a0); a1 = fmaf(v.z, lo.w, a1);
                    a2 = fmaf(v.z, hi.x, a2); a3 = fmaf(v.z, hi.y, a3);
                    a0 = fmaf(v.w, lo.y, a0); a1 = fmaf(v.w, lo.z, a1);
                    a2 = fmaf(v.w, lo.w, a2); a3 = fmaf(v.w, hi.x, a3);
                }
                const float v64 = Vs[64];
                a0 = fmaf(v64, w4[0].x, a0); a1 = fmaf(v64, w4[0].y, a1);
                a2 = fmaf(v64, w4[0].z, a2); a3 = fmaf(v64, w4[0].w, a3);
                f4 o; o.x = a0; o.y = a1; o.z = a2; o.w = a3;
                if (last) {
                    Rg4[((L + 64) >> 2) + q] = o;
                    // capture R[16192..16384) for the V2/V3 derivation:
                    // floats 8256+4q, q in [1984, 2032)
                    if (q >= 1984) reinterpret_cast<f4*>(tailb)[q - 1984] = o;
                } else {
                    Rl4w[((L + 64) >> 2) + q] = o;
                }
            }
        }
        __syncthreads();
    }

    // ===== derive V2 (level 16384), tail3 = R[32640..32768), V3 (level 32768)
    // Same formulas/fma order as the old ar_double kernels. tailb[k] = R[16192+k].
    {
        const int j = tid >> 2, c = tid & 3, mbase = c << 4;
        float w = 0.f;
        #pragma unroll
        for (int mm = 0; mm < 16; ++mm) {
            const int m = mbase + mm;
            w = fmaf(p[m + j], tailb[191 - m], w);   // R[16383-m]
        }
        Wp[j][c] = w;
    }
    __syncthreads();
    if (tid <= P) {
        const float wj  = (tid < P)
            ? (Wp[tid][0] + Wp[tid][1] + Wp[tid][2] + Wp[tid][3]) : 0.f;
        const float wm1 = (tid >= 1)
            ? (Wp[tid-1][0] + Wp[tid-1][1] + Wp[tid-1][2] + Wp[tid-1][3]) : 0.f;
        const float v = wj - wm1;
        Vs[tid] = v;
        R[VOFF + tid] = v;                            // publish V2
    }
    __syncthreads();
    if (tid < 128) {                                  // tail3[j] = R[32640+j]
        float acc = tailb[64 + tid];                  // R[16256+tid] = R[tau]
        #pragma unroll
        for (int i = 0; i <= P; ++i)
            acc = fmaf(Vs[i], tailb[64 + tid - i], acc);
        t3[tid] = acc;
    }
    __syncthreads();
    {
        const int j = tid >> 2, c = tid & 3, mbase = c << 4;
        float w = 0.f;
        #pragma unroll
        for (int mm = 0; mm < 16; ++mm) {
            const int m = mbase + mm;
            w = fmaf(p[m + j], t3[127 - m], w);       // R[32767-m]
        }
        Wp[j][c] = w;
    }
    __syncthreads();
    if (tid <= P) {
        const float wj  = (tid < P)
            ? (Wp[tid][0] + Wp[tid][1] + Wp[tid][2] + Wp[tid][3]) : 0.f;
        const float wm1 = (tid >= 1)
            ? (Wp[tid-1][0] + Wp[tid-1][1] + Wp[tid-1][2] + Wp[tid-1][3]) : 0.f;
        R[V3OFF + tid] = wj - wm1;                    // publish V3
    }

    for (int j = tid; j < K1_LEN / 4; j += K1_THREADS)
        reinterpret_cast<f4*>(R)[j] = reinterpret_cast<const f4*>(Rl)[j];
}

// ---------------------------------------------------------------------------
// Fused extension + output. Grid = 64 t-tiles x 32 batch-chunks = 2048 blocks.
// Each block builds bias*R for its 1024-wide t-tile in LDS from base
// R[0..16384) + V2/V3 (identical fma order to the old ar_double chain),
// hoists one f4 of it per thread, then streams 8 batch rows (nontemporal).
// ---------------------------------------------------------------------------
__global__ __launch_bounds__(256) void ar_out_fused(const float* __restrict__ R,
                                                    const float* __restrict__ bias,
                                                    const float* __restrict__ noise,
                                                    float* __restrict__ out) {
    __shared__ __align__(16) float Rt[W_TILE];        // bias*R for the tile
    __shared__ float winA[W_TILE + 64];               // true R over [s0, s0+W+64)
    __shared__ float winB[W_TILE + 128];              // base window for level-2 conv
    __shared__ float V2l[72], V3l[72];
    const int tid  = threadIdx.x;
    const int tile = blockIdx.x & 63;                 // 64 tiles of 1024
    const int bc   = blockIdx.x >> 6;                 // 32 chunks of 8 rows
    const int t0   = tile * W_TILE;
    const float b  = bias[0];

    if (tid < 65)       V2l[tid] = R[VOFF + tid];
    else if (tid < 130) V3l[tid - 65] = R[V3OFF + (tid - 65)];

    f4 rt;
    if (t0 < 16384) {
        // tier 0: direct, no LDS round-trip needed
        const f4 r = reinterpret_cast<const f4*>(R)[(t0 >> 2) + tid];
        rt.x = b * r.x; rt.y = b * r.y; rt.z = b * r.z; rt.w = b * r.w;
    } else if (t0 < 32768) {
        // tier 1: one V2 conv over a direct base window
        const int u0 = t0 - 16384;
        for (int k = tid; k < W_TILE + 64; k += 256) {
            const int u = u0 - 64 + k;
            winA[k] = (u >= 0) ? R[u] : 0.f;
        }
        __syncthreads();
        for (int j = tid; j < W_TILE; j += 256) {
            float acc = winA[64 + j];
            #pragma unroll
            for (int i = 0; i <= P; ++i)
                acc = fmaf(V2l[i], winA[64 + j - i], acc);
            Rt[j] = b * acc;
        }
        __syncthreads();
        rt = reinterpret_cast<const f4*>(Rt)[tid];
    } else {
        // tier 2: rebuild true R over [s0, s0+W+64) (V2 conv where needed),
        // then one V3 conv.
        const int tau0 = t0 - 32768;                  // in [0, 31744]
        const int s0   = tau0 - 64;
        if (tau0 >= 16384) {                          // some u >= 16384 needed
            const int wb0 = s0 - 16448;               // base window origin
            for (int k = tid; k < W_TILE + 128; k += 256) {
                const int u = wb0 + k;
                winB[k] = (u >= 0) ? R[u] : 0.f;
            }
        }
        __syncthreads();
        for (int k = tid; k < W_TILE + 64; k += 256) {
            const int u = s0 + k;
            float v;
            if (u < 0) {
                v = 0.f;
            } else if (u < 16384) {
                v = R[u];
            } else {
                // R[u] = R[u-16384] + sum_i V2[i]*R[u-16384-i]
                float a = winB[k + 64];
                #pragma unroll
                for (int i = 0; i <= P; ++i)
                    a = fmaf(V2l[i], winB[k + 64 - i], a);
                v = a;
            }
            winA[k] = v;
        }
        __syncthreads();
        for (int j = tid; j < W_TILE; j += 256) {
            float acc = winA[64 + j];
            #pragma unroll
            for (int i = 0; i <= P; ++i)
                acc = fmaf(V3l[i], winA[64 + j - i], acc);
            Rt[j] = b * acc;
        }
        __syncthreads();
        rt = reinterpret_cast<const f4*>(Rt)[tid];
    }

    // ---- stream 8 batch rows: 1 f4 column per thread, R hoisted in regs ----
    const int nb4 = T_LEN >> 2;                       // 16384 f4 per row
    const int col = (t0 >> 2) + tid;
    const f4* __restrict__ n4 = reinterpret_cast<const f4*>(noise);
    f4* __restrict__ o4 = reinterpret_cast<f4*>(out);
    #pragma unroll
    for (int bi = 0; bi < BCHUNK; ++bi) {
        const int idx = (bc * BCHUNK + bi) * nb4 + col;
        const f4 n = __builtin_nontemporal_load(n4 + idx);
        f4 o;
        o.x = fmaf(0.3f, n.x, rt.x);
        o.y = fmaf(0.3f, n.y, rt.y);
        o.z = fmaf(0.3f, n.z, rt.z);
        o.w = fmaf(0.3f, n.w, rt.w);
        __builtin_nontemporal_store(o, o4 + idx);
    }
}

extern "C" void kernel_launch(void* const* d_in, const int* in_sizes, int n_in,
                              void* d_out, int out_size, void* d_ws, size_t ws_size,
                              hipStream_t stream) {
    const float* params = (const float*)d_in[0];
    const float* bias   = (const float*)d_in[1];
    const float* noise  = (const float*)d_in[2];
    float* out = (float*)d_out;
    float* R   = (float*)d_ws;   // base R[0..16384) + V2/V3 at VOFF/V3OFF

    hipLaunchKernelGGL(ar_k1, dim3(1), dim3(K1_THREADS), 0, stream, params, R);
    hipLaunchKernelGGL(ar_out_fused, dim3(64 * 32), dim3(256), 0, stream,
                       R, bias, noise, out);
}

// Round 2
// 166.258 us; speedup vs baseline: 1.0145x; 1.0145x over previous
//
#include <hip/hip_runtime.h>

#define T_LEN   65536
#define BATCH   256
#define P       64
#define BASE    4096           // base length produced by the in-block ladder
#define K1_THREADS 256
#define W_TILE  1024
#define BCHUNK  8
#define VOFF    65536          // V_k published at R[VOFF + 80*k .. +64], k=1..15

typedef float f4 __attribute__((ext_vector_type(4)));

// ---------------------------------------------------------------------------
// means[t] = bias * R[t], R = step response of the AR(64) filter:
//   R[t] = sum_k params[k]*R[t-1-k] + 1,  R[t<0] = 0
// Extension identity (valid for any tau in [0, L)):
//   R[L+tau] = R[tau] + sum_{i=0}^{64} V_L[i]*R[tau-i]
//   V_L[j] = W0[j]-W0[j-1],  W0[j] = sum_{m=0}^{63-j} params[m+j]*R[L-1-m]
// R7 (this round): V is computed at EVERY multiple of 4096 (k=1..15), so each
// 1024-wide output tile is ONE 65-tap conv over base R[0..4096):
//   t = 4096k + tau, tau in [0,4096):  R[t] = R[tau] + sum V_k[i] R[tau-i]
// The V-chain needs only base sources: a +4096 step reads R[3776..4096);
// a doubling step reads the kept 256-wide tail. A 14-step ADD/DBL tree keeps
// error-compounding depth <= 6 (comparable to the old doubling ladder).
// ar_k1 loses the 8192 level + V2/V3 machinery (the bulk of its 43 us).
// ---------------------------------------------------------------------------

// tree schedule: dst node, src node, is-double, dst tail width
__constant__ int SCH_DST[14] = { 2, 3, 4, 6, 5, 7, 8,10,12,14, 9,11,13,15};
__constant__ int SCH_SRC[14] = { 1, 2, 2, 3, 4, 6, 4, 5, 6, 7, 8,10,12,14};
__constant__ int SCH_DBL[14] = { 1, 0, 1, 1, 0, 0, 1, 1, 1, 1, 0, 0, 0, 0};
__constant__ int SCH_W[14]   = {192,256,128,192,256,256,64,192,128,192,256,256,256,256};

__global__ __launch_bounds__(K1_THREADS, 1) void ar_k1(const float* __restrict__ params,
                                                       float* __restrict__ R) {
    __shared__ __align__(16) float Rl[BASE];
    __shared__ float p[128];          // zero-padded: p[64..127] = 0 masks m+j>63
    __shared__ float Wp[64][4];
    __shared__ __align__(16) float Vs[68];
    __shared__ __align__(16) float Vnode[16][68];   // V_k, k=1..15
    __shared__ __align__(16) float Tn[8][256];      // kept tails, nodes 1..7
    __shared__ __align__(16) float Ts[256];         // transient tail, nodes >=8
    const int tid = threadIdx.x;
    if (tid < 128) p[tid] = (tid < P) ? params[tid] : 0.f;
    __syncthreads();

    // Serial stage: lane k holds transposed-form state z_{k+1}.
    if (tid < 64) {
        float z = 0.f;
        const float pk = p[tid];
        for (int t = 0; t < 64; ++t) {
            float y  = __shfl(z, 0) + 1.0f;   // R[t]
            float zn = __shfl_down(z, 1);
            if (tid == 63) zn = 0.f;
            z = fmaf(pk, y, zn);
            if (tid == 0) Rl[t] = y;
        }
    }
    __syncthreads();

    // Doubling ladder 64 -> 4096, all in LDS (verified level code, no 8192).
    for (int L = 64; L <= BASE / 2; L <<= 1) {
        {   // V taps, wave-parallel
            const int j = tid >> 2, c = tid & 3;
            const int mbase = c << 4;
            float w = 0.f;
            #pragma unroll
            for (int mm = 0; mm < 16; ++mm) {
                const int m = mbase + mm;
                w = fmaf(p[m + j], Rl[L - 1 - m], w);  // p pad masks m+j>63
            }
            Wp[j][c] = w;
        }
        __syncthreads();
        if (tid <= P) {
            const float wj  = (tid < P)
                ? (Wp[tid][0] + Wp[tid][1] + Wp[tid][2] + Wp[tid][3]) : 0.f;
            const float wm1 = (tid >= 1)
                ? (Wp[tid-1][0] + Wp[tid-1][1] + Wp[tid-1][2] + Wp[tid-1][3]) : 0.f;
            Vs[tid] = wj - wm1;
        }
        __syncthreads();
        // boundary outputs tau in [0,64)
        if (tid < P) {
            const int tau = tid;
            float acc = Rl[tau];
            #pragma unroll
            for (int i = 0; i < P; ++i) {
                const int idx = (tau - i) > 0 ? (tau - i) : 0;
                const float v = (i <= tau) ? Vs[i] : 0.f;
                acc = fmaf(v, Rl[idx], acc);
            }
            Rl[L + tau] = acc;
        }
        // blocked outputs tau in [64,L)
        {
            const f4* __restrict__ Rl4 = reinterpret_cast<const f4*>(Rl);
            f4* __restrict__ Rl4w = reinterpret_cast<f4*>(Rl);
            const f4* __restrict__ V4 = reinterpret_cast<const f4*>(Vs);
            const int nq = (L - 64) >> 2;
            #pragma unroll 1
            for (int q = tid; q < nq; q += K1_THREADS) {
                f4 w4[17];
                #pragma unroll
                for (int j = 0; j < 17; ++j) w4[j] = Rl4[q + j];
                float a0 = w4[16].x, a1 = w4[16].y, a2 = w4[16].z, a3 = w4[16].w;
                #pragma unroll
                for (int g = 0; g < 16; ++g) {   // i = 4g..4g+3
                    const f4 v  = V4[g];
                    const f4 hi = w4[16 - g];
                    const f4 lo = w4[15 - g];
                    a0 = fmaf(v.x, hi.x, a0); a1 = fmaf(v.x, hi.y, a1);
                    a2 = fmaf(v.x, hi.z, a2); a3 = fmaf(v.x, hi.w, a3);
                    a0 = fmaf(v.y, lo.w, a0); a1 = fmaf(v.y, hi.x, a1);
                    a2 = fmaf(v.y, hi.y, a2); a3 = fmaf(v.y, hi.z, a3);
                    a0 = fmaf(v.z, lo.z, a0); a1 = fmaf(v.z, lo.w, a1);
                    a2 = fmaf(v.z, hi.x, a2); a3 = fmaf(v.z, hi.y, a3);
                    a0 = fmaf(v.w, lo.y, a0); a1 = fmaf(v.w, lo.z, a1);
                    a2 = fmaf(v.w, lo.w, a2); a3 = fmaf(v.w, hi.x, a3);
                }
                const float v64 = Vs[64];
                a0 = fmaf(v64, w4[0].x, a0); a1 = fmaf(v64, w4[0].y, a1);
                a2 = fmaf(v64, w4[0].z, a2); a3 = fmaf(v64, w4[0].w, a3);
                f4 o; o.x = a0; o.y = a1; o.z = a2; o.w = a3;
                Rl4w[((L + 64) >> 2) + q] = o;
            }
        }
        __syncthreads();
    }

    // publish base R[0..4096)
    for (int j = tid; j < BASE / 4; j += K1_THREADS)
        reinterpret_cast<f4*>(R)[j] = reinterpret_cast<const f4*>(Rl)[j];

    // ----- node 1: tail = R[3840..4096), tap -> V_4096 -----
    Tn[1][tid] = Rl[3840 + tid];
    __syncthreads();
    {
        const int j = tid >> 2, c = tid & 3, mbase = c << 4;
        float w = 0.f;
        #pragma unroll
        for (int mm = 0; mm < 16; ++mm) {
            const int m = mbase + mm;
            w = fmaf(p[m + j], Tn[1][255 - m], w);    // R[4095-m]
        }
        Wp[j][c] = w;
    }
    __syncthreads();
    if (tid <= P) {
        const float wj  = (tid < P)
            ? (Wp[tid][0] + Wp[tid][1] + Wp[tid][2] + Wp[tid][3]) : 0.f;
        const float wm1 = (tid >= 1)
            ? (Wp[tid-1][0] + Wp[tid-1][1] + Wp[tid-1][2] + Wp[tid-1][3]) : 0.f;
        Vnode[1][tid] = wj - wm1;
    }
    __syncthreads();

    // ----- 14 tree steps: ADD (+4096, base sources) / DBL (tail sources) -----
    for (int s = 0; s < 14; ++s) {
        const int dst = SCH_DST[s], src = SCH_SRC[s], wd = SCH_W[s];
        const bool dbl = SCH_DBL[s] != 0;
        float* td = (dst <= 7) ? Tn[dst] : Ts;
        const float* tsrc = Tn[src];
        const float* Vsr  = Vnode[src];
        if (tid < wd) {
            const float* s0 = dbl ? (tsrc + 64) : (Rl + 3840);
            float acc = s0[tid];
            #pragma unroll
            for (int i = 0; i <= P; ++i)
                acc = fmaf(Vsr[i], s0[tid - i], acc);
            td[tid] = acc;
        }
        __syncthreads();
        {
            const int j = tid >> 2, c = tid & 3, mbase = c << 4;
            float w = 0.f;
            #pragma unroll
            for (int mm = 0; mm < 16; ++mm) {
                const int m = mbase + mm;
                w = fmaf(p[m + j], td[wd - 1 - m], w);
            }
            Wp[j][c] = w;
        }
        __syncthreads();
        if (tid <= P) {
            const float wj  = (tid < P)
                ? (Wp[tid][0] + Wp[tid][1] + Wp[tid][2] + Wp[tid][3]) : 0.f;
            const float wm1 = (tid >= 1)
                ? (Wp[tid-1][0] + Wp[tid-1][1] + Wp[tid-1][2] + Wp[tid-1][3]) : 0.f;
            Vnode[dst][tid] = wj - wm1;
        }
        __syncthreads();
    }

    // publish V_1..V_15
    for (int j = tid; j < 15 * 80; j += K1_THREADS) {
        const int k = j / 80 + 1, i = j - (k - 1) * 80;
        if (i < 65) R[VOFF + k * 80 + i] = Vnode[k][i];
    }
}

// ---------------------------------------------------------------------------
// Fused extension + output, UNIFORM: tile [t0, t0+1024) with k = t0>>12,
// tau0 = t0 & 4095: R[t] = win[64+x] + sum_i V_k[i]*win[64+x-i], conv result
// stays in the thread's streaming registers (no Rt LDS round-trip).
// Grid = 64 t-tiles x 32 batch-chunks = 2048 blocks (1 pass over the chip).
// ---------------------------------------------------------------------------
__global__ __launch_bounds__(256) void ar_out_fused(const float* __restrict__ R,
                                                    const float* __restrict__ bias,
                                                    const float* __restrict__ noise,
                                                    float* __restrict__ out) {
    __shared__ __align__(16) float win[1088];   // R[tau0-64 .. tau0+1024)
    __shared__ __align__(16) float Vl[68];
    const int tid  = threadIdx.x;
    const int tile = blockIdx.x & 63;
    const int bc   = blockIdx.x >> 6;
    const int t0   = tile * W_TILE;
    const float b  = bias[0];
    const int k    = t0 >> 12;                  // 0..15
    const f4* __restrict__ Rg4 = reinterpret_cast<const f4*>(R);

    f4 rt;
    if (k == 0) {
        const f4 r = Rg4[(t0 >> 2) + tid];      // bitwise-identical base path
        rt.x = b * r.x; rt.y = b * r.y; rt.z = b * r.z; rt.w = b * r.w;
    } else {
        const int tau0 = t0 & 4095;
        if (tid < 65) Vl[tid] = R[VOFF + k * 80 + tid];
        f4* __restrict__ win4 = reinterpret_cast<f4*>(win);
        for (int j4 = tid; j4 < 272; j4 += 256) {
            const int u = tau0 - 64 + 4 * j4;   // multiple of 4
            f4 v;
            if (u >= 0) v = Rg4[u >> 2];
            else { v.x = 0.f; v.y = 0.f; v.z = 0.f; v.w = 0.f; }
            win4[j4] = v;
        }
        __syncthreads();
        // 65-tap conv, f4-blocked (same index algebra as the ladder's loop)
        const f4* __restrict__ V4 = reinterpret_cast<const f4*>(Vl);
        f4 w4[17];
        #pragma unroll
        for (int j = 0; j < 17; ++j) w4[j] = win4[tid + j];
        float a0 = w4[16].x, a1 = w4[16].y, a2 = w4[16].z, a3 = w4[16].w;
        #pragma unroll
        for (int g = 0; g < 16; ++g) {
            const f4 v  = V4[g];
            const f4 hi = w4[16 - g];
            const f4 lo = w4[15 - g];
            a0 = fmaf(v.x, hi.x, a0); a1 = fmaf(v.x, hi.y, a1);
            a2 = fmaf(v.x, hi.z, a2); a3 = fmaf(v.x, hi.w, a3);
            a0 = fmaf(v.y, lo.w, a0); a1 = fmaf(v.y, hi.x, a1);
            a2 = fmaf(v.y, hi.y, a2); a3 = fmaf(v.y, hi.z, a3);
            a0 = fmaf(v.z, lo.z, a0); a1 = fmaf(v.z, lo.w, a1);
            a2 = fmaf(v.z, hi.x, a2); a3 = fmaf(v.z, hi.y, a3);
            a0 = fmaf(v.w, lo.y, a0); a1 = fmaf(v.w, lo.z, a1);
            a2 = fmaf(v.w, lo.w, a2); a3 = fmaf(v.w, hi.x, a3);
        }
        const float v64 = Vl[64];
        a0 = fmaf(v64, w4[0].x, a0); a1 = fmaf(v64, w4[0].y, a1);
        a2 = fmaf(v64, w4[0].z, a2); a3 = fmaf(v64, w4[0].w, a3);
        rt.x = b * a0; rt.y = b * a1; rt.z = b * a2; rt.w = b * a3;
    }

    // stream 8 batch rows: 1 f4 column per thread, R tile in registers
    const int nb4 = T_LEN >> 2;
    const int col = (t0 >> 2) + tid;
    const f4* __restrict__ n4 = reinterpret_cast<const f4*>(noise);
    f4* __restrict__ o4 = reinterpret_cast<f4*>(out);
    #pragma unroll
    for (int bi = 0; bi < BCHUNK; ++bi) {
        const int idx = (bc * BCHUNK + bi) * nb4 + col;
        const f4 n = __builtin_nontemporal_load(n4 + idx);
        f4 o;
        o.x = fmaf(0.3f, n.x, rt.x);
        o.y = fmaf(0.3f, n.y, rt.y);
        o.z = fmaf(0.3f, n.z, rt.z);
        o.w = fmaf(0.3f, n.w, rt.w);
        __builtin_nontemporal_store(o, o4 + idx);
    }
}

extern "C" void kernel_launch(void* const* d_in, const int* in_sizes, int n_in,
                              void* d_out, int out_size, void* d_ws, size_t ws_size,
                              hipStream_t stream) {
    const float* params = (const float*)d_in[0];
    const float* bias   = (const float*)d_in[1];
    const float* noise  = (const float*)d_in[2];
    float* out = (float*)d_out;
    float* R   = (float*)d_ws;   // base R[0..4096) + V_1..15 at VOFF

    hipLaunchKernelGGL(ar_k1, dim3(1), dim3(K1_THREADS), 0, stream, params, R);
    hipLaunchKernelGGL(ar_out_fused, dim3(64 * 32), dim3(256), 0, stream,
                       R, bias, noise, out);
}